// Round 16
// baseline (35.021 us; speedup 1.0000x reference)
//
#include <hip/hip_runtime.h>

// Bottom-up HTMM upward pass — 3 launches (+ 1 tiny memset).
// r16 change vs r12-optimum: leaf log-scale terms moved out of upleaf via a
// g-independent symbol histogram — count[t][l][m] built in prep's xpack pass
// (LDS histogram + deterministic integer global atomics), folded into uptop
// as a 256-term dot with ltab. upleaf's leaf loop: 5 -> 4 LDS reads/leaf.
// Tree structure implicit: starts[d]=(8^d-1)/7, child position == local%8.

constexpr int NT_NODES = 299593;
constexpr int S0 = 0, S1 = 1, S2 = 9, S3 = 73, S4 = 585, S5 = 4681, S6 = 37449;

__device__ __forceinline__ unsigned bfbits(float x) {   // f32 -> bf16 bits, RNE
    unsigned v = __float_as_uint(x);
    return (v + 0x7fffu + ((v >> 16) & 1u)) >> 16;
}

__device__ __forceinline__ float sel8(const float v[8], bool c0, bool c1, bool c2) {
    float a0 = c0 ? v[1] : v[0];
    float a1 = c0 ? v[3] : v[2];
    float a2 = c0 ? v[5] : v[4];
    float a3 = c0 ? v[7] : v[6];
    float b0 = c1 ? a1 : a0;
    float b1 = c1 ? a3 : a2;
    return c2 ? b1 : b0;
}

// ---------------- prep: tables (blocks 0-15) + xpack/histogram (16-271) ----------------
//   MtN   [g][l][j][i] : 8192 f32  (= smSP[l,g]*smA[i,j,l,g])
//   smBtN [g][m][c]    : 4096 f32
//   Tp    [g][k][256]  : k=0..3 bf16 pairs of T row, k=4 f32 ltab
//   EMp   [g][k][32]   : bf16 pairs of emission rows
//   rec[t*32768+p]     : {8 leaf bytes, mid|root<<8|x3<<16, 0}
//   cntLM [t][l][m]    : 512 ints, leaf-symbol histogram (zeroed per launch)
__global__ __launch_bounds__(256) void prep(
    const float* __restrict__ A, const float* __restrict__ B,
    const float* __restrict__ Pi, const float* __restrict__ SP,
    const int* __restrict__ x,
    float* __restrict__ MtN, float* __restrict__ smBtN,
    unsigned* __restrict__ Tp, unsigned* __restrict__ EMp,
    uint4* __restrict__ rec, int* __restrict__ cntLM)
{
    int bid = blockIdx.x;
    int tid = threadIdx.x;

    if (bid >= 16) {
        // ---- xpack + leaf histogram (block is single-tree: 256 | 32768) ----
        __shared__ int h[256];
        h[tid] = 0;
        __syncthreads();

        int pidx = (bid - 16) * 256 + tid;   // 0..65535
        int t = pidx >> 15, localP = pidx & 32767;
        const int base = t * NT_NODES;
        const int xb = base + S6 + localP * 8;
        int xs[8];
        #pragma unroll
        for (int l = 0; l < 8; ++l) xs[l] = x[xb + l];
        unsigned d0 = 0, d1 = 0;
        #pragma unroll
        for (int l = 0; l < 4; ++l) d0 |= ((unsigned)xs[l]) << (8 * l);
        #pragma unroll
        for (int l = 0; l < 4; ++l) d1 |= ((unsigned)xs[4 + l]) << (8 * l);
        unsigned xm = (unsigned)x[base + S5 + localP];
        unsigned xr = (unsigned)x[base + S4 + (localP >> 3)];
        unsigned x3 = (unsigned)x[base + S3 + (localP >> 6)];
        rec[pidx] = make_uint4(d0, d1, xm | (xr << 8) | (x3 << 16), 0u);

        // leaf position l == leaf index within parent
        #pragma unroll
        for (int l = 0; l < 8; ++l) atomicAdd(&h[l * 32 + xs[l]], 1);
        __syncthreads();
        if (h[tid]) atomicAdd(&cntLM[t * 256 + tid], h[tid]);
        return;
    }

    // ---- tables for g = bid ----
    int g = bid;
    __shared__ __align__(16) float mL[512];   // [l][j][i]
    __shared__ __align__(16) float bLs[256];  // [m][c]
    __shared__ __align__(16) float piLs[64];  // [l][c]

    float sp[8];
    {
        float mx = -1e30f;
        #pragma unroll
        for (int l = 0; l < 8; ++l) { sp[l] = SP[l * 16 + g]; mx = fmaxf(mx, sp[l]); }
        float s = 0.f;
        #pragma unroll
        for (int l = 0; l < 8; ++l) { sp[l] = __expf(sp[l] - mx); s += sp[l]; }
        float r = 1.f / s;
        #pragma unroll
        for (int l = 0; l < 8; ++l) sp[l] *= r;
    }

    if (tid < 64) {
        int j = tid & 7, l = tid >> 3;
        float a[8]; float mx = -1e30f;
        #pragma unroll
        for (int i = 0; i < 8; ++i) { a[i] = A[((i * 8 + j) * 8 + l) * 16 + g]; mx = fmaxf(mx, a[i]); }
        float s = 0.f;
        #pragma unroll
        for (int i = 0; i < 8; ++i) { a[i] = __expf(a[i] - mx); s += a[i]; }
        float scale = sp[l] / s;
        #pragma unroll
        for (int i = 0; i < 8; ++i) {
            float m = a[i] * scale;
            mL[(l * 8 + j) * 8 + i] = m;
            MtN[((g * 8 + l) * 8 + j) * 8 + i] = m;
        }
    } else if (tid < 72) {
        int c = tid - 64;
        float vv[32]; float mx = -1e30f;
        #pragma unroll
        for (int m = 0; m < 32; ++m) { vv[m] = B[(c * 32 + m) * 16 + g]; mx = fmaxf(mx, vv[m]); }
        float s = 0.f;
        #pragma unroll
        for (int m = 0; m < 32; ++m) { vv[m] = __expf(vv[m] - mx); s += vv[m]; }
        float r = 1.f / s;
        #pragma unroll
        for (int m = 0; m < 32; ++m) {
            float p = vv[m] * r;
            bLs[m * 8 + c] = p;
            smBtN[(g * 32 + m) * 8 + c] = p;
        }
    } else if (tid < 80) {
        int l = tid - 72;
        float a[8]; float mx = -1e30f;
        #pragma unroll
        for (int c = 0; c < 8; ++c) { a[c] = Pi[(c * 8 + l) * 16 + g]; mx = fmaxf(mx, a[c]); }
        float s = 0.f;
        #pragma unroll
        for (int c = 0; c < 8; ++c) { a[c] = __expf(a[c] - mx); s += a[c]; }
        float r = 1.f / s;
        #pragma unroll
        for (int c = 0; c < 8; ++c) piLs[l * 8 + c] = a[c] * r;
    }
    __syncthreads();

    {
        int m = tid & 31, l = tid >> 5;
        float pb[8]; float w = 0.f;
        #pragma unroll
        for (int c = 0; c < 8; ++c) { pb[c] = piLs[l * 8 + c] * bLs[m * 8 + c]; w += pb[c]; }
        float rw = 1.f / w;
        float t[8];
        #pragma unroll
        for (int i = 0; i < 8; ++i) t[i] = 0.f;
        #pragma unroll
        for (int c = 0; c < 8; ++c) {
            float p = pb[c];
            #pragma unroll
            for (int i = 0; i < 8; ++i) t[i] = fmaf(p, mL[(l * 8 + c) * 8 + i], t[i]);
        }
        #pragma unroll
        for (int k = 0; k < 4; ++k) {
            unsigned lo = bfbits(t[2 * k] * rw), hi = bfbits(t[2 * k + 1] * rw);
            Tp[(g * 5 + k) * 256 + tid] = lo | (hi << 16);
        }
        Tp[(g * 5 + 4) * 256 + tid] = __float_as_uint(__logf(w));
    }
    if (tid < 32) {
        #pragma unroll
        for (int k = 0; k < 4; ++k) {
            unsigned lo = bfbits(bLs[tid * 8 + 2 * k]), hi = bfbits(bLs[tid * 8 + 2 * k + 1]);
            EMp[(g * 4 + k) * 32 + tid] = lo | (hi << 16);
        }
    }
}

// ---------------- upleaf: levels 6->5->4->3, thread = HALF subtree ----------------
// grid = 64 pg * 16 g = 1024 blocks, 256 thr = 4 waves. Block covers 128
// subtrees of ONE g (single tree: 128 | 4096) = 16 level-3 nodes.
// Waves 2w,2w+1 pair on subtrees [pg*128 + w*64 .. +63]; half = wave&1.
// Leaf ll terms are NOT accumulated here (histogram path) -> 4 reads/leaf.
__global__ __launch_bounds__(256, 4) void upleaf(
    const float* __restrict__ MtN, const unsigned* __restrict__ Tp,
    const unsigned* __restrict__ EMp, const uint4* __restrict__ rec,
    float* __restrict__ lv3,     // [g][1024][8]
    float* __restrict__ llout)   // [g][64]
{
    __shared__ unsigned TL[256 * 5 + 32 * 5];
    __shared__ float ex[128 * 9];     // pair-exchange / root betas, stride 9
    __shared__ float llp[4];

    int bid = blockIdx.x;
    int g = bid & 15;
    int pg = bid >> 4;                 // 0..63
    int tid = threadIdx.x;
    int wave = tid >> 6;
    int lane = tid & 63;
    int half = wave & 1;               // wave-uniform
    int pairIdx = wave >> 1;
    int gu = __builtin_amdgcn_readfirstlane(g);
    int idx = pairIdx * 64 + lane;     // block-local subtree 0..127
    int s = pg * 128 + idx;            // level-4 subtree 0..8191
    int t = (s >= 4096) ? 1 : 0;
    int localS = s - t * 4096;

    // fill LDS tables (stride 5: gcd(5,32)=1 -> divergent reads conflict-free)
    #pragma unroll
    for (int k = 0; k < 5; ++k)
        TL[tid * 5 + k] = Tp[(gu * 5 + k) * 256 + tid];
    if (tid < 32) {
        #pragma unroll
        for (int k = 0; k < 4; ++k)
            TL[1280 + tid * 5 + k] = EMp[(gu * 4 + k) * 32 + tid];
    }

    // this thread's 4 parent records (64B contiguous)
    uint4 rc[4];
    {
        const uint4* rp = rec + ((size_t)t * 32768 + (size_t)localS * 8 + half * 4);
        #pragma unroll
        for (int u = 0; u < 4; ++u) rc[u] = rp[u];
    }
    unsigned meta = rc[0].z;
    int xr = (meta >> 8) & 255;        // level-4 root symbol
    unsigned x3b = (meta >> 16) & 255; // level-3 symbol
    __syncthreads();

    float ll = 0.f;
    float bm[32];    // normalized mid betas [u][c] for this half

    // ---- 4 mid parents: leaves via T-table (4 reads/leaf), emission+normalize ----
    #pragma unroll
    for (int u = 0; u < 4; ++u) {
        int xl[8];
        xl[0] = rc[u].x & 255; xl[1] = (rc[u].x >> 8) & 255;
        xl[2] = (rc[u].x >> 16) & 255; xl[3] = rc[u].x >> 24;
        xl[4] = rc[u].y & 255; xl[5] = (rc[u].y >> 8) & 255;
        xl[6] = (rc[u].y >> 16) & 255; xl[7] = rc[u].y >> 24;
        int xm = rc[u].z & 255;

        float pa[8] = {0.f, 0.f, 0.f, 0.f, 0.f, 0.f, 0.f, 0.f};
        #pragma unroll
        for (int l = 0; l < 8; ++l) {
            int r5 = (l * 32 + xl[l]) * 5;
            unsigned u0 = TL[r5], u1 = TL[r5 + 1], u2 = TL[r5 + 2], u3 = TL[r5 + 3];
            pa[0] += __uint_as_float(u0 << 16); pa[1] += __uint_as_float(u0 & 0xffff0000u);
            pa[2] += __uint_as_float(u1 << 16); pa[3] += __uint_as_float(u1 & 0xffff0000u);
            pa[4] += __uint_as_float(u2 << 16); pa[5] += __uint_as_float(u2 & 0xffff0000u);
            pa[6] += __uint_as_float(u3 << 16); pa[7] += __uint_as_float(u3 & 0xffff0000u);
        }
        int e5 = 1280 + xm * 5;
        unsigned e0 = TL[e5], e1 = TL[e5 + 1], e2 = TL[e5 + 2], e3 = TL[e5 + 3];
        pa[0] *= __uint_as_float(e0 << 16); pa[1] *= __uint_as_float(e0 & 0xffff0000u);
        pa[2] *= __uint_as_float(e1 << 16); pa[3] *= __uint_as_float(e1 & 0xffff0000u);
        pa[4] *= __uint_as_float(e2 << 16); pa[5] *= __uint_as_float(e2 & 0xffff0000u);
        pa[6] *= __uint_as_float(e3 << 16); pa[7] *= __uint_as_float(e3 & 0xffff0000u);
        float nu = ((pa[0] + pa[1]) + (pa[2] + pa[3])) + ((pa[4] + pa[5]) + (pa[6] + pa[7]));
        ll += __logf(nu);
        float rn = __builtin_amdgcn_rcpf(nu);
        #pragma unroll
        for (int c = 0; c < 8; ++c) bm[u * 8 + c] = pa[c] * rn;
    }

    // ---- root partial: 256 FMA over this half, M via SCALAR loads ----
    float pr[8] = {0.f, 0.f, 0.f, 0.f, 0.f, 0.f, 0.f, 0.f};
    {
        const float* Mg = MtN + (gu << 9) + (half << 8);
        #pragma unroll
        for (int k = 0; k < 32; ++k) {
            float b = bm[k];
            #pragma unroll
            for (int i = 0; i < 8; ++i) pr[i] = fmaf(b, Mg[k * 8 + i], pr[i]);
        }
    }
    if (half) {
        #pragma unroll
        for (int c = 0; c < 8; ++c) ex[idx * 9 + c] = pr[c];
    }
    __syncthreads();
    if (!half) {
        float tot[8];
        #pragma unroll
        for (int c = 0; c < 8; ++c) tot[c] = pr[c] + ex[idx * 9 + c];
        int e5 = 1280 + xr * 5;
        unsigned e0 = TL[e5], e1 = TL[e5 + 1], e2 = TL[e5 + 2], e3 = TL[e5 + 3];
        tot[0] *= __uint_as_float(e0 << 16); tot[1] *= __uint_as_float(e0 & 0xffff0000u);
        tot[2] *= __uint_as_float(e1 << 16); tot[3] *= __uint_as_float(e1 & 0xffff0000u);
        tot[4] *= __uint_as_float(e2 << 16); tot[5] *= __uint_as_float(e2 & 0xffff0000u);
        tot[6] *= __uint_as_float(e3 << 16); tot[7] *= __uint_as_float(e3 & 0xffff0000u);
        float nur = ((tot[0] + tot[1]) + (tot[2] + tot[3])) + ((tot[4] + tot[5]) + (tot[6] + tot[7]));
        ll += __logf(nur);
        float rr = __builtin_amdgcn_rcpf(nur);
        #pragma unroll
        for (int c = 0; c < 8; ++c) ex[idx * 9 + c] = tot[c] * rr;   // root beta
        ex[idx * 9 + 8] = __uint_as_float(x3b);                       // stash x3
    }
    __syncthreads();

    // ---- level 4 -> 3: 16 nodes, octet scheme on threads 0..127 ----
    if (tid < 128) {
        int o = tid >> 3, j = tid & 7;
        int s3 = pg * 16 + o;                // global level-3 index 0..1023
        float bch[8];
        #pragma unroll
        for (int l = 0; l < 8; ++l) bch[l] = ex[(o * 8 + l) * 9 + j];
        float pr3[8] = {0.f, 0.f, 0.f, 0.f, 0.f, 0.f, 0.f, 0.f};
        #pragma unroll
        for (int l = 0; l < 8; ++l) {
            const float4* mp = (const float4*)(MtN + (gu << 9) + (l << 6) + (j << 3));
            float4 m0 = mp[0], m1 = mp[1];
            float b = bch[l];
            pr3[0] = fmaf(b, m0.x, pr3[0]); pr3[1] = fmaf(b, m0.y, pr3[1]);
            pr3[2] = fmaf(b, m0.z, pr3[2]); pr3[3] = fmaf(b, m0.w, pr3[3]);
            pr3[4] = fmaf(b, m1.x, pr3[4]); pr3[5] = fmaf(b, m1.y, pr3[5]);
            pr3[6] = fmaf(b, m1.z, pr3[6]); pr3[7] = fmaf(b, m1.w, pr3[7]);
        }
        #pragma unroll
        for (int m = 1; m <= 4; m <<= 1) {
            #pragma unroll
            for (int i = 0; i < 8; ++i) pr3[i] += __shfl_xor(pr3[i], m);
        }
        int xn = (int)__float_as_uint(ex[(o * 8) * 9 + 8]);
        int e5 = 1280 + xn * 5;
        unsigned e0 = TL[e5], e1 = TL[e5 + 1], e2 = TL[e5 + 2], e3 = TL[e5 + 3];
        pr3[0] *= __uint_as_float(e0 << 16); pr3[1] *= __uint_as_float(e0 & 0xffff0000u);
        pr3[2] *= __uint_as_float(e1 << 16); pr3[3] *= __uint_as_float(e1 & 0xffff0000u);
        pr3[4] *= __uint_as_float(e2 << 16); pr3[5] *= __uint_as_float(e2 & 0xffff0000u);
        pr3[6] *= __uint_as_float(e3 << 16); pr3[7] *= __uint_as_float(e3 & 0xffff0000u);
        float nur = ((pr3[0] + pr3[1]) + (pr3[2] + pr3[3])) + ((pr3[4] + pr3[5]) + (pr3[6] + pr3[7]));
        float rr = __builtin_amdgcn_rcpf(nur);
        if (j == 0) {
            ll += __logf(nur);
            float4* dp = (float4*)(lv3 + ((size_t)g * 1024 + s3) * 8);
            dp[0] = make_float4(pr3[0] * rr, pr3[1] * rr, pr3[2] * rr, pr3[3] * rr);
            dp[1] = make_float4(pr3[4] * rr, pr3[5] * rr, pr3[6] * rr, pr3[7] * rr);
        }
    }

    // ---- block ll reduce -> llout[g][pg] (block is single-tree) ----
    #pragma unroll
    for (int m = 1; m < 64; m <<= 1) ll += __shfl_xor(ll, m);
    if (lane == 0) llp[wave] = ll;
    __syncthreads();
    if (tid == 0) llout[gu * 64 + pg] = (llp[0] + llp[1]) + (llp[2] + llp[3]);
}

// ---------------- uptop: one block per g — levels 3->2->1->0 + output ----------------
__global__ __launch_bounds__(256) void uptop(
    const float* __restrict__ MtN, const float* __restrict__ smBtN,
    const int* __restrict__ x,
    const float* __restrict__ lv3,   // [g][1024][8]
    const float* __restrict__ ll1,   // [g][64]  (pg<32: tree0, pg>=32: tree1)
    const unsigned* __restrict__ Tp, // ltab plane: Tp[(g*5+4)*256 + l*32+m]
    const int* __restrict__ cntLM,   // [t][256] leaf-symbol histogram
    float* __restrict__ out)         // [2][16]
{
    int g = blockIdx.x;   // 0..15
    int tid = threadIdx.x;
    __shared__ __align__(16) float bet2[128 * 8];
    __shared__ __align__(16) float bet1[16 * 8];
    __shared__ float redA[256], redB[256];

    float ll0 = 0.f, llt1 = 0.f;
    if (tid < 64) {
        float v = ll1[g * 64 + tid];
        if (tid < 32) ll0 = v; else llt1 = v;
    }
    // leaf ll via histogram: bin (l,m) = tid, one per thread per tree
    {
        float lt = __uint_as_float(Tp[(g * 5 + 4) * 256 + tid]);
        ll0  += (float)cntLM[tid]       * lt;
        llt1 += (float)cntLM[256 + tid] * lt;
    }

    const float* Mg = MtN + (g << 9);

    // ---- phase A: level 3 -> 2 (128 tasks, 1/thread) ----
    if (tid < 128) {
        int t = tid >> 6, n2 = tid & 63;
        float bch[64];
        const float4* sp = (const float4*)(lv3 + ((size_t)g * 1024 + t * 512 + n2 * 8) * 8);
        #pragma unroll
        for (int v = 0; v < 16; ++v) {
            float4 f = sp[v];
            bch[4 * v + 0] = f.x; bch[4 * v + 1] = f.y;
            bch[4 * v + 2] = f.z; bch[4 * v + 3] = f.w;
        }
        float pa[8] = {0.f, 0.f, 0.f, 0.f, 0.f, 0.f, 0.f, 0.f};
        #pragma unroll
        for (int k = 0; k < 64; ++k) {
            float b = bch[k];
            #pragma unroll
            for (int i = 0; i < 8; ++i) pa[i] = fmaf(b, Mg[k * 8 + i], pa[i]);
        }
        int x2 = x[t * NT_NODES + S2 + n2];
        const float4* ep = (const float4*)(smBtN + ((g << 5) + x2) * 8);
        float4 e0 = ep[0], e1 = ep[1];
        pa[0] *= e0.x; pa[1] *= e0.y; pa[2] *= e0.z; pa[3] *= e0.w;
        pa[4] *= e1.x; pa[5] *= e1.y; pa[6] *= e1.z; pa[7] *= e1.w;
        float nu = ((pa[0] + pa[1]) + (pa[2] + pa[3])) + ((pa[4] + pa[5]) + (pa[6] + pa[7]));
        float lg = __logf(nu);
        if (t == 0) ll0 += lg; else llt1 += lg;
        float rn = __builtin_amdgcn_rcpf(nu);
        float4* dp = (float4*)(bet2 + tid * 8);
        dp[0] = make_float4(pa[0] * rn, pa[1] * rn, pa[2] * rn, pa[3] * rn);
        dp[1] = make_float4(pa[4] * rn, pa[5] * rn, pa[6] * rn, pa[7] * rn);
    }
    __syncthreads();

    // ---- phase B: level 2 -> 1 (16 nodes, octet scheme on threads 0..127) ----
    if (tid < 128) {
        int o = tid >> 3, j = tid & 7;
        int t = o >> 3, n1 = o & 7;
        bool c0 = (j & 1) != 0, c1 = (j & 2) != 0, c2 = (j & 4) != 0;
        float bch[8];
        #pragma unroll
        for (int l = 0; l < 8; ++l) bch[l] = bet2[(t * 64 + n1 * 8 + l) * 8 + j];
        float pr[8] = {0.f, 0.f, 0.f, 0.f, 0.f, 0.f, 0.f, 0.f};
        #pragma unroll
        for (int l = 0; l < 8; ++l) {
            const float4* mp = (const float4*)(MtN + (g << 9) + (l << 6) + (j << 3));
            float4 m0 = mp[0], m1 = mp[1];
            float b = bch[l];
            pr[0] = fmaf(b, m0.x, pr[0]); pr[1] = fmaf(b, m0.y, pr[1]);
            pr[2] = fmaf(b, m0.z, pr[2]); pr[3] = fmaf(b, m0.w, pr[3]);
            pr[4] = fmaf(b, m1.x, pr[4]); pr[5] = fmaf(b, m1.y, pr[5]);
            pr[6] = fmaf(b, m1.z, pr[6]); pr[7] = fmaf(b, m1.w, pr[7]);
        }
        #pragma unroll
        for (int m = 1; m <= 4; m <<= 1) {
            #pragma unroll
            for (int i = 0; i < 8; ++i) pr[i] += __shfl_xor(pr[i], m);
        }
        int x1 = x[t * NT_NODES + S1 + n1];
        const float4* ep = (const float4*)(smBtN + ((g << 5) + x1) * 8);
        float4 e0 = ep[0], e1 = ep[1];
        pr[0] *= e0.x; pr[1] *= e0.y; pr[2] *= e0.z; pr[3] *= e0.w;
        pr[4] *= e1.x; pr[5] *= e1.y; pr[6] *= e1.z; pr[7] *= e1.w;
        float nu = ((pr[0] + pr[1]) + (pr[2] + pr[3])) + ((pr[4] + pr[5]) + (pr[6] + pr[7]));
        if (j == 0) { float lg = __logf(nu); if (t == 0) ll0 += lg; else llt1 += lg; }
        float rn = __builtin_amdgcn_rcpf(nu);
        bet1[o * 8 + j] = sel8(pr, c0, c1, c2) * rn;
    }
    __syncthreads();

    // ---- phase C: level 1 -> 0 (2 roots, octets on threads 0..15) ----
    if (tid < 16) {
        int t = tid >> 3, j = tid & 7;
        float bch[8];
        #pragma unroll
        for (int l = 0; l < 8; ++l) bch[l] = bet1[(t * 8 + l) * 8 + j];
        float pr[8] = {0.f, 0.f, 0.f, 0.f, 0.f, 0.f, 0.f, 0.f};
        #pragma unroll
        for (int l = 0; l < 8; ++l) {
            const float4* mp = (const float4*)(MtN + (g << 9) + (l << 6) + (j << 3));
            float4 m0 = mp[0], m1 = mp[1];
            float b = bch[l];
            pr[0] = fmaf(b, m0.x, pr[0]); pr[1] = fmaf(b, m0.y, pr[1]);
            pr[2] = fmaf(b, m0.z, pr[2]); pr[3] = fmaf(b, m0.w, pr[3]);
            pr[4] = fmaf(b, m1.x, pr[4]); pr[5] = fmaf(b, m1.y, pr[5]);
            pr[6] = fmaf(b, m1.z, pr[6]); pr[7] = fmaf(b, m1.w, pr[7]);
        }
        #pragma unroll
        for (int m = 1; m <= 4; m <<= 1) {
            #pragma unroll
            for (int i = 0; i < 8; ++i) pr[i] += __shfl_xor(pr[i], m);
        }
        int x0 = x[t * NT_NODES + S0];
        const float4* ep = (const float4*)(smBtN + ((g << 5) + x0) * 8);
        float4 e0 = ep[0], e1 = ep[1];
        pr[0] *= e0.x; pr[1] *= e0.y; pr[2] *= e0.z; pr[3] *= e0.w;
        pr[4] *= e1.x; pr[5] *= e1.y; pr[6] *= e1.z; pr[7] *= e1.w;
        float nu = ((pr[0] + pr[1]) + (pr[2] + pr[3])) + ((pr[4] + pr[5]) + (pr[6] + pr[7]));
        if (j == 0) { float lg = __logf(nu); if (t == 0) ll0 += lg; else llt1 += lg; }
    }

    // ---- deterministic block reduction -> out[2][16] ----
    redA[tid] = ll0; redB[tid] = llt1;
    __syncthreads();
    for (int step = 128; step > 0; step >>= 1) {
        if (tid < step) { redA[tid] += redA[tid + step]; redB[tid] += redB[tid + step]; }
        __syncthreads();
    }
    if (tid == 0) { out[g] = redA[0]; out[16 + g] = redB[0]; }
}

extern "C" void kernel_launch(void* const* d_in, const int* in_sizes, int n_in,
                              void* d_out, int out_size, void* d_ws, size_t ws_size,
                              hipStream_t stream)
{
    const float* A  = (const float*)d_in[0];
    const float* B  = (const float*)d_in[1];
    const float* Pi = (const float*)d_in[2];
    const float* SP = (const float*)d_in[3];
    const int*   x  = (const int*)d_in[4];

    float* ws     = (float*)d_ws;
    float* MtN    = ws;                        // 8192
    float* smBtN  = MtN + 8192;                // 4096
    unsigned* Tp  = (unsigned*)(smBtN + 4096); // 20480
    unsigned* EMp = Tp + 20480;                // 2048
    uint4* rec    = (uint4*)(EMp + 2048);      // 65536 * 16B
    float* lv3    = (float*)(rec + 65536);     // 131072
    float* ll1    = lv3 + 131072;              // 16*64 = 1024
    int* cntLM    = (int*)(ll1 + 1024);        // 512
    float* out    = (float*)d_out;

    // zero the histogram each launch (ws is not re-poisoned between replays)
    hipMemsetAsync(cntLM, 0, 512 * sizeof(int), stream);
    // tables (blocks 0-15) + symbol packing/histogram (blocks 16-271)
    prep<<<272, 256, 0, stream>>>(A, B, Pi, SP, x, MtN, smBtN, Tp, EMp, rec, cntLM);
    // levels 6 -> 5 -> 4 -> 3 : thread = half a level-4 subtree
    upleaf<<<1024, 256, 0, stream>>>(MtN, Tp, EMp, rec, lv3, ll1);
    // levels 3 -> 2 -> 1 -> 0 (+ fold ll1 + histogram leaf-ll), writes out[2][16]
    uptop<<<16, 256, 0, stream>>>(MtN, smBtN, x, lv3, ll1, Tp, cntLM, out);
}

// Round 17
// 29.787 us; speedup vs baseline: 1.1757x; 1.1757x over previous
//
#include <hip/hip_runtime.h>

// Bottom-up HTMM upward pass — 3 launches. (Round-12 verified optimum, 29.8us,
// reproduced in r15. Reverted after r13 b64-restride (-2.7us), r14 fused
// finish (-78us, __threadfence serialization), r16 leaf-ll histogram (-5.2us,
// memset node + prep atomics > upleaf savings) all regressed.)
// prep  : blocks 0-15 build per-g packed tables; blocks 16-271 pack each
//         level-5 parent's symbols {8 leaves, mid, L4root, L3} into 16B.
// upleaf: levels 6->5->4->3. Thread = HALF a level-4 subtree (4 mid-parents);
//         waves 2w/2w+1 pair on the same 64 subtrees with wave-uniform half
//         bit, so the 256-FMA root partial streams M via SCALAR loads; halves
//         combine through a stride-9 LDS buffer. 1024 blocks -> 4 waves/SIMD.
// uptop : one block per g, levels 3->2->1->0 + ll folding -> out[2][16].
// Tree structure implicit: starts[d]=(8^d-1)/7, child position == local%8.

constexpr int NT_NODES = 299593;
constexpr int S0 = 0, S1 = 1, S2 = 9, S3 = 73, S4 = 585, S5 = 4681, S6 = 37449;

__device__ __forceinline__ unsigned bfbits(float x) {   // f32 -> bf16 bits, RNE
    unsigned v = __float_as_uint(x);
    return (v + 0x7fffu + ((v >> 16) & 1u)) >> 16;
}

__device__ __forceinline__ float sel8(const float v[8], bool c0, bool c1, bool c2) {
    float a0 = c0 ? v[1] : v[0];
    float a1 = c0 ? v[3] : v[2];
    float a2 = c0 ? v[5] : v[4];
    float a3 = c0 ? v[7] : v[6];
    float b0 = c1 ? a1 : a0;
    float b1 = c1 ? a3 : a2;
    return c2 ? b1 : b0;
}

// ---------------- prep: tables (blocks 0-15) + xpack (blocks 16-271) ----------------
//   MtN   [g][l][j][i] : 8192 f32  (= smSP[l,g]*smA[i,j,l,g])
//   smBtN [g][m][c]    : 4096 f32
//   Tp    [g][k][256]  : k=0..3 bf16 pairs of T row, k=4 f32 ltab
//   EMp   [g][k][32]   : bf16 pairs of emission rows
//   rec[t*32768+p]     : {8 leaf bytes, mid|root<<8|x3<<16, 0}
__global__ __launch_bounds__(256) void prep(
    const float* __restrict__ A, const float* __restrict__ B,
    const float* __restrict__ Pi, const float* __restrict__ SP,
    const int* __restrict__ x,
    float* __restrict__ MtN, float* __restrict__ smBtN,
    unsigned* __restrict__ Tp, unsigned* __restrict__ EMp,
    uint4* __restrict__ rec)
{
    int bid = blockIdx.x;
    int tid = threadIdx.x;

    if (bid >= 16) {
        // ---- xpack ----
        int pidx = (bid - 16) * 256 + tid;   // 0..65535
        int t = pidx >> 15, localP = pidx & 32767;
        const int base = t * NT_NODES;
        const int xb = base + S6 + localP * 8;
        unsigned d0 = 0, d1 = 0;
        #pragma unroll
        for (int l = 0; l < 4; ++l) d0 |= ((unsigned)x[xb + l]) << (8 * l);
        #pragma unroll
        for (int l = 0; l < 4; ++l) d1 |= ((unsigned)x[xb + 4 + l]) << (8 * l);
        unsigned xm = (unsigned)x[base + S5 + localP];
        unsigned xr = (unsigned)x[base + S4 + (localP >> 3)];
        unsigned x3 = (unsigned)x[base + S3 + (localP >> 6)];
        rec[pidx] = make_uint4(d0, d1, xm | (xr << 8) | (x3 << 16), 0u);
        return;
    }

    // ---- tables for g = bid ----
    int g = bid;
    __shared__ __align__(16) float mL[512];   // [l][j][i]
    __shared__ __align__(16) float bLs[256];  // [m][c]
    __shared__ __align__(16) float piLs[64];  // [l][c]

    float sp[8];
    {
        float mx = -1e30f;
        #pragma unroll
        for (int l = 0; l < 8; ++l) { sp[l] = SP[l * 16 + g]; mx = fmaxf(mx, sp[l]); }
        float s = 0.f;
        #pragma unroll
        for (int l = 0; l < 8; ++l) { sp[l] = __expf(sp[l] - mx); s += sp[l]; }
        float r = 1.f / s;
        #pragma unroll
        for (int l = 0; l < 8; ++l) sp[l] *= r;
    }

    if (tid < 64) {
        int j = tid & 7, l = tid >> 3;
        float a[8]; float mx = -1e30f;
        #pragma unroll
        for (int i = 0; i < 8; ++i) { a[i] = A[((i * 8 + j) * 8 + l) * 16 + g]; mx = fmaxf(mx, a[i]); }
        float s = 0.f;
        #pragma unroll
        for (int i = 0; i < 8; ++i) { a[i] = __expf(a[i] - mx); s += a[i]; }
        float scale = sp[l] / s;
        #pragma unroll
        for (int i = 0; i < 8; ++i) {
            float m = a[i] * scale;
            mL[(l * 8 + j) * 8 + i] = m;
            MtN[((g * 8 + l) * 8 + j) * 8 + i] = m;
        }
    } else if (tid < 72) {
        int c = tid - 64;
        float vv[32]; float mx = -1e30f;
        #pragma unroll
        for (int m = 0; m < 32; ++m) { vv[m] = B[(c * 32 + m) * 16 + g]; mx = fmaxf(mx, vv[m]); }
        float s = 0.f;
        #pragma unroll
        for (int m = 0; m < 32; ++m) { vv[m] = __expf(vv[m] - mx); s += vv[m]; }
        float r = 1.f / s;
        #pragma unroll
        for (int m = 0; m < 32; ++m) {
            float p = vv[m] * r;
            bLs[m * 8 + c] = p;
            smBtN[(g * 32 + m) * 8 + c] = p;
        }
    } else if (tid < 80) {
        int l = tid - 72;
        float a[8]; float mx = -1e30f;
        #pragma unroll
        for (int c = 0; c < 8; ++c) { a[c] = Pi[(c * 8 + l) * 16 + g]; mx = fmaxf(mx, a[c]); }
        float s = 0.f;
        #pragma unroll
        for (int c = 0; c < 8; ++c) { a[c] = __expf(a[c] - mx); s += a[c]; }
        float r = 1.f / s;
        #pragma unroll
        for (int c = 0; c < 8; ++c) piLs[l * 8 + c] = a[c] * r;
    }
    __syncthreads();

    {
        int m = tid & 31, l = tid >> 5;
        float pb[8]; float w = 0.f;
        #pragma unroll
        for (int c = 0; c < 8; ++c) { pb[c] = piLs[l * 8 + c] * bLs[m * 8 + c]; w += pb[c]; }
        float rw = 1.f / w;
        float t[8];
        #pragma unroll
        for (int i = 0; i < 8; ++i) t[i] = 0.f;
        #pragma unroll
        for (int c = 0; c < 8; ++c) {
            float p = pb[c];
            #pragma unroll
            for (int i = 0; i < 8; ++i) t[i] = fmaf(p, mL[(l * 8 + c) * 8 + i], t[i]);
        }
        #pragma unroll
        for (int k = 0; k < 4; ++k) {
            unsigned lo = bfbits(t[2 * k] * rw), hi = bfbits(t[2 * k + 1] * rw);
            Tp[(g * 5 + k) * 256 + tid] = lo | (hi << 16);
        }
        Tp[(g * 5 + 4) * 256 + tid] = __float_as_uint(__logf(w));
    }
    if (tid < 32) {
        #pragma unroll
        for (int k = 0; k < 4; ++k) {
            unsigned lo = bfbits(bLs[tid * 8 + 2 * k]), hi = bfbits(bLs[tid * 8 + 2 * k + 1]);
            EMp[(g * 4 + k) * 32 + tid] = lo | (hi << 16);
        }
    }
}

// ---------------- upleaf: levels 6->5->4->3, thread = HALF subtree ----------------
// grid = 64 pg * 16 g = 1024 blocks, 256 thr = 4 waves. Block covers 128
// subtrees of ONE g (single tree: 128 | 4096) = 16 level-3 nodes.
// Waves 2w,2w+1 pair on subtrees [pg*128 + w*64 .. +63]; half = wave&1.
__global__ __launch_bounds__(256, 4) void upleaf(
    const float* __restrict__ MtN, const unsigned* __restrict__ Tp,
    const unsigned* __restrict__ EMp, const uint4* __restrict__ rec,
    float* __restrict__ lv3,     // [g][1024][8]
    float* __restrict__ llout)   // [g][64]
{
    __shared__ unsigned TL[256 * 5 + 32 * 5];
    __shared__ float ex[128 * 9];     // pair-exchange / root betas, stride 9
    __shared__ float llp[4];

    int bid = blockIdx.x;
    int g = bid & 15;
    int pg = bid >> 4;                 // 0..63
    int tid = threadIdx.x;
    int wave = tid >> 6;
    int lane = tid & 63;
    int half = wave & 1;               // wave-uniform
    int pairIdx = wave >> 1;
    int gu = __builtin_amdgcn_readfirstlane(g);
    int idx = pairIdx * 64 + lane;     // block-local subtree 0..127
    int s = pg * 128 + idx;            // level-4 subtree 0..8191
    int t = (s >= 4096) ? 1 : 0;
    int localS = s - t * 4096;

    // fill LDS tables (stride 5: gcd(5,32)=1 -> divergent reads conflict-free)
    #pragma unroll
    for (int k = 0; k < 5; ++k)
        TL[tid * 5 + k] = Tp[(gu * 5 + k) * 256 + tid];
    if (tid < 32) {
        #pragma unroll
        for (int k = 0; k < 4; ++k)
            TL[1280 + tid * 5 + k] = EMp[(gu * 4 + k) * 32 + tid];
    }

    // this thread's 4 parent records (64B contiguous)
    uint4 rc[4];
    {
        const uint4* rp = rec + ((size_t)t * 32768 + (size_t)localS * 8 + half * 4);
        #pragma unroll
        for (int u = 0; u < 4; ++u) rc[u] = rp[u];
    }
    unsigned meta = rc[0].z;
    int xr = (meta >> 8) & 255;        // level-4 root symbol
    unsigned x3b = (meta >> 16) & 255; // level-3 symbol
    __syncthreads();

    float ll = 0.f;
    float bm[32];    // normalized mid betas [u][c] for this half

    // ---- 4 mid parents: leaves via T-table, then emission+normalize ----
    #pragma unroll
    for (int u = 0; u < 4; ++u) {
        int xl[8];
        xl[0] = rc[u].x & 255; xl[1] = (rc[u].x >> 8) & 255;
        xl[2] = (rc[u].x >> 16) & 255; xl[3] = rc[u].x >> 24;
        xl[4] = rc[u].y & 255; xl[5] = (rc[u].y >> 8) & 255;
        xl[6] = (rc[u].y >> 16) & 255; xl[7] = rc[u].y >> 24;
        int xm = rc[u].z & 255;

        float pa[8] = {0.f, 0.f, 0.f, 0.f, 0.f, 0.f, 0.f, 0.f};
        #pragma unroll
        for (int l = 0; l < 8; ++l) {
            int r5 = (l * 32 + xl[l]) * 5;
            unsigned u0 = TL[r5], u1 = TL[r5 + 1], u2 = TL[r5 + 2], u3 = TL[r5 + 3];
            ll += __uint_as_float(TL[r5 + 4]);
            pa[0] += __uint_as_float(u0 << 16); pa[1] += __uint_as_float(u0 & 0xffff0000u);
            pa[2] += __uint_as_float(u1 << 16); pa[3] += __uint_as_float(u1 & 0xffff0000u);
            pa[4] += __uint_as_float(u2 << 16); pa[5] += __uint_as_float(u2 & 0xffff0000u);
            pa[6] += __uint_as_float(u3 << 16); pa[7] += __uint_as_float(u3 & 0xffff0000u);
        }
        int e5 = 1280 + xm * 5;
        unsigned e0 = TL[e5], e1 = TL[e5 + 1], e2 = TL[e5 + 2], e3 = TL[e5 + 3];
        pa[0] *= __uint_as_float(e0 << 16); pa[1] *= __uint_as_float(e0 & 0xffff0000u);
        pa[2] *= __uint_as_float(e1 << 16); pa[3] *= __uint_as_float(e1 & 0xffff0000u);
        pa[4] *= __uint_as_float(e2 << 16); pa[5] *= __uint_as_float(e2 & 0xffff0000u);
        pa[6] *= __uint_as_float(e3 << 16); pa[7] *= __uint_as_float(e3 & 0xffff0000u);
        float nu = ((pa[0] + pa[1]) + (pa[2] + pa[3])) + ((pa[4] + pa[5]) + (pa[6] + pa[7]));
        ll += __logf(nu);
        float rn = __builtin_amdgcn_rcpf(nu);
        #pragma unroll
        for (int c = 0; c < 8; ++c) bm[u * 8 + c] = pa[c] * rn;
    }

    // ---- root partial: 256 FMA over this half, M via SCALAR loads ----
    float pr[8] = {0.f, 0.f, 0.f, 0.f, 0.f, 0.f, 0.f, 0.f};
    {
        const float* Mg = MtN + (gu << 9) + (half << 8);
        #pragma unroll
        for (int k = 0; k < 32; ++k) {
            float b = bm[k];
            #pragma unroll
            for (int i = 0; i < 8; ++i) pr[i] = fmaf(b, Mg[k * 8 + i], pr[i]);
        }
    }
    if (half) {
        #pragma unroll
        for (int c = 0; c < 8; ++c) ex[idx * 9 + c] = pr[c];
    }
    __syncthreads();
    if (!half) {
        float tot[8];
        #pragma unroll
        for (int c = 0; c < 8; ++c) tot[c] = pr[c] + ex[idx * 9 + c];
        int e5 = 1280 + xr * 5;
        unsigned e0 = TL[e5], e1 = TL[e5 + 1], e2 = TL[e5 + 2], e3 = TL[e5 + 3];
        tot[0] *= __uint_as_float(e0 << 16); tot[1] *= __uint_as_float(e0 & 0xffff0000u);
        tot[2] *= __uint_as_float(e1 << 16); tot[3] *= __uint_as_float(e1 & 0xffff0000u);
        tot[4] *= __uint_as_float(e2 << 16); tot[5] *= __uint_as_float(e2 & 0xffff0000u);
        tot[6] *= __uint_as_float(e3 << 16); tot[7] *= __uint_as_float(e3 & 0xffff0000u);
        float nur = ((tot[0] + tot[1]) + (tot[2] + tot[3])) + ((tot[4] + tot[5]) + (tot[6] + tot[7]));
        ll += __logf(nur);
        float rr = __builtin_amdgcn_rcpf(nur);
        #pragma unroll
        for (int c = 0; c < 8; ++c) ex[idx * 9 + c] = tot[c] * rr;   // root beta
        ex[idx * 9 + 8] = __uint_as_float(x3b);                       // stash x3
    }
    __syncthreads();

    // ---- level 4 -> 3: 16 nodes, octet scheme on threads 0..127 ----
    if (tid < 128) {
        int o = tid >> 3, j = tid & 7;
        int s3 = pg * 16 + o;                // global level-3 index 0..1023
        float bch[8];
        #pragma unroll
        for (int l = 0; l < 8; ++l) bch[l] = ex[(o * 8 + l) * 9 + j];
        float pr3[8] = {0.f, 0.f, 0.f, 0.f, 0.f, 0.f, 0.f, 0.f};
        #pragma unroll
        for (int l = 0; l < 8; ++l) {
            const float4* mp = (const float4*)(MtN + (gu << 9) + (l << 6) + (j << 3));
            float4 m0 = mp[0], m1 = mp[1];
            float b = bch[l];
            pr3[0] = fmaf(b, m0.x, pr3[0]); pr3[1] = fmaf(b, m0.y, pr3[1]);
            pr3[2] = fmaf(b, m0.z, pr3[2]); pr3[3] = fmaf(b, m0.w, pr3[3]);
            pr3[4] = fmaf(b, m1.x, pr3[4]); pr3[5] = fmaf(b, m1.y, pr3[5]);
            pr3[6] = fmaf(b, m1.z, pr3[6]); pr3[7] = fmaf(b, m1.w, pr3[7]);
        }
        #pragma unroll
        for (int m = 1; m <= 4; m <<= 1) {
            #pragma unroll
            for (int i = 0; i < 8; ++i) pr3[i] += __shfl_xor(pr3[i], m);
        }
        int xn = (int)__float_as_uint(ex[(o * 8) * 9 + 8]);
        int e5 = 1280 + xn * 5;
        unsigned e0 = TL[e5], e1 = TL[e5 + 1], e2 = TL[e5 + 2], e3 = TL[e5 + 3];
        pr3[0] *= __uint_as_float(e0 << 16); pr3[1] *= __uint_as_float(e0 & 0xffff0000u);
        pr3[2] *= __uint_as_float(e1 << 16); pr3[3] *= __uint_as_float(e1 & 0xffff0000u);
        pr3[4] *= __uint_as_float(e2 << 16); pr3[5] *= __uint_as_float(e2 & 0xffff0000u);
        pr3[6] *= __uint_as_float(e3 << 16); pr3[7] *= __uint_as_float(e3 & 0xffff0000u);
        float nur = ((pr3[0] + pr3[1]) + (pr3[2] + pr3[3])) + ((pr3[4] + pr3[5]) + (pr3[6] + pr3[7]));
        float rr = __builtin_amdgcn_rcpf(nur);
        if (j == 0) {
            ll += __logf(nur);
            float4* dp = (float4*)(lv3 + ((size_t)g * 1024 + s3) * 8);
            dp[0] = make_float4(pr3[0] * rr, pr3[1] * rr, pr3[2] * rr, pr3[3] * rr);
            dp[1] = make_float4(pr3[4] * rr, pr3[5] * rr, pr3[6] * rr, pr3[7] * rr);
        }
    }

    // ---- block ll reduce -> llout[g][pg] (block is single-tree) ----
    #pragma unroll
    for (int m = 1; m < 64; m <<= 1) ll += __shfl_xor(ll, m);
    if (lane == 0) llp[wave] = ll;
    __syncthreads();
    if (tid == 0) llout[gu * 64 + pg] = (llp[0] + llp[1]) + (llp[2] + llp[3]);
}

// ---------------- uptop: one block per g — levels 3->2->1->0 + output ----------------
__global__ __launch_bounds__(256) void uptop(
    const float* __restrict__ MtN, const float* __restrict__ smBtN,
    const int* __restrict__ x,
    const float* __restrict__ lv3,   // [g][1024][8]
    const float* __restrict__ ll1,   // [g][64]  (pg<32: tree0, pg>=32: tree1)
    float* __restrict__ out)         // [2][16]
{
    int g = blockIdx.x;   // 0..15
    int tid = threadIdx.x;
    __shared__ __align__(16) float bet2[128 * 8];
    __shared__ __align__(16) float bet1[16 * 8];
    __shared__ float redA[256], redB[256];

    float ll0 = 0.f, llt1 = 0.f;
    if (tid < 64) {
        float v = ll1[g * 64 + tid];
        if (tid < 32) ll0 = v; else llt1 = v;
    }

    const float* Mg = MtN + (g << 9);

    // ---- phase A: level 3 -> 2 (128 tasks, 1/thread) ----
    if (tid < 128) {
        int t = tid >> 6, n2 = tid & 63;
        float bch[64];
        const float4* sp = (const float4*)(lv3 + ((size_t)g * 1024 + t * 512 + n2 * 8) * 8);
        #pragma unroll
        for (int v = 0; v < 16; ++v) {
            float4 f = sp[v];
            bch[4 * v + 0] = f.x; bch[4 * v + 1] = f.y;
            bch[4 * v + 2] = f.z; bch[4 * v + 3] = f.w;
        }
        float pa[8] = {0.f, 0.f, 0.f, 0.f, 0.f, 0.f, 0.f, 0.f};
        #pragma unroll
        for (int k = 0; k < 64; ++k) {
            float b = bch[k];
            #pragma unroll
            for (int i = 0; i < 8; ++i) pa[i] = fmaf(b, Mg[k * 8 + i], pa[i]);
        }
        int x2 = x[t * NT_NODES + S2 + n2];
        const float4* ep = (const float4*)(smBtN + ((g << 5) + x2) * 8);
        float4 e0 = ep[0], e1 = ep[1];
        pa[0] *= e0.x; pa[1] *= e0.y; pa[2] *= e0.z; pa[3] *= e0.w;
        pa[4] *= e1.x; pa[5] *= e1.y; pa[6] *= e1.z; pa[7] *= e1.w;
        float nu = ((pa[0] + pa[1]) + (pa[2] + pa[3])) + ((pa[4] + pa[5]) + (pa[6] + pa[7]));
        float lg = __logf(nu);
        if (t == 0) ll0 += lg; else llt1 += lg;
        float rn = __builtin_amdgcn_rcpf(nu);
        float4* dp = (float4*)(bet2 + tid * 8);
        dp[0] = make_float4(pa[0] * rn, pa[1] * rn, pa[2] * rn, pa[3] * rn);
        dp[1] = make_float4(pa[4] * rn, pa[5] * rn, pa[6] * rn, pa[7] * rn);
    }
    __syncthreads();

    // ---- phase B: level 2 -> 1 (16 nodes, octet scheme on threads 0..127) ----
    if (tid < 128) {
        int o = tid >> 3, j = tid & 7;
        int t = o >> 3, n1 = o & 7;
        bool c0 = (j & 1) != 0, c1 = (j & 2) != 0, c2 = (j & 4) != 0;
        float bch[8];
        #pragma unroll
        for (int l = 0; l < 8; ++l) bch[l] = bet2[(t * 64 + n1 * 8 + l) * 8 + j];
        float pr[8] = {0.f, 0.f, 0.f, 0.f, 0.f, 0.f, 0.f, 0.f};
        #pragma unroll
        for (int l = 0; l < 8; ++l) {
            const float4* mp = (const float4*)(MtN + (g << 9) + (l << 6) + (j << 3));
            float4 m0 = mp[0], m1 = mp[1];
            float b = bch[l];
            pr[0] = fmaf(b, m0.x, pr[0]); pr[1] = fmaf(b, m0.y, pr[1]);
            pr[2] = fmaf(b, m0.z, pr[2]); pr[3] = fmaf(b, m0.w, pr[3]);
            pr[4] = fmaf(b, m1.x, pr[4]); pr[5] = fmaf(b, m1.y, pr[5]);
            pr[6] = fmaf(b, m1.z, pr[6]); pr[7] = fmaf(b, m1.w, pr[7]);
        }
        #pragma unroll
        for (int m = 1; m <= 4; m <<= 1) {
            #pragma unroll
            for (int i = 0; i < 8; ++i) pr[i] += __shfl_xor(pr[i], m);
        }
        int x1 = x[t * NT_NODES + S1 + n1];
        const float4* ep = (const float4*)(smBtN + ((g << 5) + x1) * 8);
        float4 e0 = ep[0], e1 = ep[1];
        pr[0] *= e0.x; pr[1] *= e0.y; pr[2] *= e0.z; pr[3] *= e0.w;
        pr[4] *= e1.x; pr[5] *= e1.y; pr[6] *= e1.z; pr[7] *= e1.w;
        float nu = ((pr[0] + pr[1]) + (pr[2] + pr[3])) + ((pr[4] + pr[5]) + (pr[6] + pr[7]));
        if (j == 0) { float lg = __logf(nu); if (t == 0) ll0 += lg; else llt1 += lg; }
        float rn = __builtin_amdgcn_rcpf(nu);
        bet1[o * 8 + j] = sel8(pr, c0, c1, c2) * rn;
    }
    __syncthreads();

    // ---- phase C: level 1 -> 0 (2 roots, octets on threads 0..15) ----
    if (tid < 16) {
        int t = tid >> 3, j = tid & 7;
        float bch[8];
        #pragma unroll
        for (int l = 0; l < 8; ++l) bch[l] = bet1[(t * 8 + l) * 8 + j];
        float pr[8] = {0.f, 0.f, 0.f, 0.f, 0.f, 0.f, 0.f, 0.f};
        #pragma unroll
        for (int l = 0; l < 8; ++l) {
            const float4* mp = (const float4*)(MtN + (g << 9) + (l << 6) + (j << 3));
            float4 m0 = mp[0], m1 = mp[1];
            float b = bch[l];
            pr[0] = fmaf(b, m0.x, pr[0]); pr[1] = fmaf(b, m0.y, pr[1]);
            pr[2] = fmaf(b, m0.z, pr[2]); pr[3] = fmaf(b, m0.w, pr[3]);
            pr[4] = fmaf(b, m1.x, pr[4]); pr[5] = fmaf(b, m1.y, pr[5]);
            pr[6] = fmaf(b, m1.z, pr[6]); pr[7] = fmaf(b, m1.w, pr[7]);
        }
        #pragma unroll
        for (int m = 1; m <= 4; m <<= 1) {
            #pragma unroll
            for (int i = 0; i < 8; ++i) pr[i] += __shfl_xor(pr[i], m);
        }
        int x0 = x[t * NT_NODES + S0];
        const float4* ep = (const float4*)(smBtN + ((g << 5) + x0) * 8);
        float4 e0 = ep[0], e1 = ep[1];
        pr[0] *= e0.x; pr[1] *= e0.y; pr[2] *= e0.z; pr[3] *= e0.w;
        pr[4] *= e1.x; pr[5] *= e1.y; pr[6] *= e1.z; pr[7] *= e1.w;
        float nu = ((pr[0] + pr[1]) + (pr[2] + pr[3])) + ((pr[4] + pr[5]) + (pr[6] + pr[7]));
        if (j == 0) { float lg = __logf(nu); if (t == 0) ll0 += lg; else llt1 += lg; }
    }

    // ---- deterministic block reduction -> out[2][16] ----
    redA[tid] = ll0; redB[tid] = llt1;
    __syncthreads();
    for (int step = 128; step > 0; step >>= 1) {
        if (tid < step) { redA[tid] += redA[tid + step]; redB[tid] += redB[tid + step]; }
        __syncthreads();
    }
    if (tid == 0) { out[g] = redA[0]; out[16 + g] = redB[0]; }
}

extern "C" void kernel_launch(void* const* d_in, const int* in_sizes, int n_in,
                              void* d_out, int out_size, void* d_ws, size_t ws_size,
                              hipStream_t stream)
{
    const float* A  = (const float*)d_in[0];
    const float* B  = (const float*)d_in[1];
    const float* Pi = (const float*)d_in[2];
    const float* SP = (const float*)d_in[3];
    const int*   x  = (const int*)d_in[4];

    float* ws     = (float*)d_ws;
    float* MtN    = ws;                        // 8192
    float* smBtN  = MtN + 8192;                // 4096
    unsigned* Tp  = (unsigned*)(smBtN + 4096); // 20480
    unsigned* EMp = Tp + 20480;                // 2048
    uint4* rec    = (uint4*)(EMp + 2048);      // 65536 * 16B
    float* lv3    = (float*)(rec + 65536);     // 131072
    float* ll1    = lv3 + 131072;              // 16*64 = 1024
    float* out    = (float*)d_out;

    // tables (blocks 0-15) + symbol packing (blocks 16-271)
    prep<<<272, 256, 0, stream>>>(A, B, Pi, SP, x, MtN, smBtN, Tp, EMp, rec);
    // levels 6 -> 5 -> 4 -> 3 : thread = half a level-4 subtree
    upleaf<<<1024, 256, 0, stream>>>(MtN, Tp, EMp, rec, lv3, ll1);
    // levels 3 -> 2 -> 1 -> 0 (+ fold ll1), writes out[2][16]
    uptop<<<16, 256, 0, stream>>>(MtN, smBtN, x, lv3, ll1, out);
}